// Round 9
// baseline (165.655 us; speedup 1.0000x reference)
//
#include <hip/hip_runtime.h>
#include <hip/hip_bf16.h>
#include <cstdint>

typedef unsigned short u16;
typedef __attribute__((ext_vector_type(8))) short short8;
typedef __attribute__((ext_vector_type(4))) float f32x4;

#define B_ 32
#define H_ 8
#define S_ 512
#define C_ 64

struct alignas(8) u32x2 { uint32_t x, y; };
union U8 { short8 s; uint32_t u[4]; };

__device__ __forceinline__ u16 f2bf(float f) {
    uint32_t u = __builtin_bit_cast(uint32_t, f);
    u += 0x7fffu + ((u >> 16) & 1u);   // RNE
    return (u16)(u >> 16);
}

#if __has_builtin(__builtin_amdgcn_cvt_pk_bf16_f32)
__device__ __forceinline__ uint32_t pack_bf16(float a, float b) {
    auto r = __builtin_amdgcn_cvt_pk_bf16_f32(a, b);   // v_cvt_pk_bf16_f32 (RNE)
    return __builtin_bit_cast(uint32_t, r);
}
#else
__device__ __forceinline__ uint32_t pack_bf16(float a, float b) {
    return (uint32_t)f2bf(a) | ((uint32_t)f2bf(b) << 16);
}
#endif

__device__ __forceinline__ float bfhi(uint32_t pk) {   // high bf16 -> f32
    return __builtin_bit_cast(float, pk & 0xffff0000u);
}
__device__ __forceinline__ float bflo(uint32_t pk) {   // low bf16 -> f32
    return __builtin_bit_cast(float, pk << 16);
}

// ================= k_inv: one thread per (b,n) frame inverse =================
__global__ __launch_bounds__(64) void k_inv(
    const float* __restrict__ lf, float* __restrict__ minv)
{
    const int idx = blockIdx.x * 64 + threadIdx.x;   // 0 .. B*S-1
    const float* m = lf + (size_t)idx * 16;
    float a[16];
#pragma unroll
    for (int j = 0; j < 16; ++j) a[j] = m[j];
    float inv[16];
    inv[0]  =  a[5]*a[10]*a[15] - a[5]*a[11]*a[14] - a[9]*a[6]*a[15] + a[9]*a[7]*a[14] + a[13]*a[6]*a[11] - a[13]*a[7]*a[10];
    inv[4]  = -a[4]*a[10]*a[15] + a[4]*a[11]*a[14] + a[8]*a[6]*a[15] - a[8]*a[7]*a[14] - a[12]*a[6]*a[11] + a[12]*a[7]*a[10];
    inv[8]  =  a[4]*a[9]*a[15] - a[4]*a[11]*a[13] - a[8]*a[5]*a[15] + a[8]*a[7]*a[13] + a[12]*a[5]*a[11] - a[12]*a[7]*a[9];
    inv[12] = -a[4]*a[9]*a[14] + a[4]*a[10]*a[13] + a[8]*a[5]*a[14] - a[8]*a[6]*a[13] - a[12]*a[5]*a[10] + a[12]*a[6]*a[9];
    inv[1]  = -a[1]*a[10]*a[15] + a[1]*a[11]*a[14] + a[9]*a[2]*a[15] - a[9]*a[3]*a[14] - a[13]*a[2]*a[11] + a[13]*a[3]*a[10];
    inv[5]  =  a[0]*a[10]*a[15] - a[0]*a[11]*a[14] - a[8]*a[2]*a[15] + a[8]*a[3]*a[14] + a[12]*a[2]*a[11] - a[12]*a[3]*a[10];
    inv[9]  = -a[0]*a[9]*a[15] + a[0]*a[11]*a[13] + a[8]*a[1]*a[15] - a[8]*a[3]*a[13] - a[12]*a[1]*a[11] + a[12]*a[3]*a[9];
    inv[13] =  a[0]*a[9]*a[14] - a[0]*a[10]*a[13] - a[8]*a[1]*a[14] + a[8]*a[2]*a[13] + a[12]*a[1]*a[10] - a[12]*a[2]*a[9];
    inv[2]  =  a[1]*a[6]*a[15] - a[1]*a[7]*a[14] - a[5]*a[2]*a[15] + a[5]*a[3]*a[14] + a[13]*a[2]*a[7] - a[13]*a[3]*a[6];
    inv[6]  = -a[0]*a[6]*a[15] + a[0]*a[7]*a[14] + a[4]*a[2]*a[15] - a[4]*a[3]*a[14] - a[12]*a[2]*a[7] + a[12]*a[3]*a[6];
    inv[10] =  a[0]*a[5]*a[15] - a[0]*a[7]*a[13] - a[4]*a[1]*a[15] + a[4]*a[3]*a[13] + a[12]*a[1]*a[7] - a[12]*a[3]*a[5];
    inv[14] = -a[0]*a[5]*a[14] + a[0]*a[6]*a[13] + a[4]*a[1]*a[14] - a[4]*a[2]*a[13] - a[12]*a[1]*a[6] + a[12]*a[2]*a[5];
    inv[3]  = -a[1]*a[6]*a[11] + a[1]*a[7]*a[10] + a[5]*a[2]*a[11] - a[5]*a[3]*a[10] - a[9]*a[2]*a[7] + a[9]*a[3]*a[6];
    inv[7]  =  a[0]*a[6]*a[11] - a[0]*a[7]*a[10] - a[4]*a[2]*a[11] + a[4]*a[3]*a[10] + a[8]*a[2]*a[7] - a[8]*a[3]*a[6];
    inv[11] = -a[0]*a[5]*a[11] + a[0]*a[7]*a[9] + a[4]*a[1]*a[11] - a[4]*a[3]*a[9] - a[8]*a[1]*a[7] + a[8]*a[3]*a[5];
    inv[15] =  a[0]*a[5]*a[10] - a[0]*a[6]*a[9] - a[4]*a[1]*a[10] + a[4]*a[2]*a[9] + a[8]*a[1]*a[6] - a[8]*a[2]*a[5];
    float det = a[0]*inv[0] + a[1]*inv[4] + a[2]*inv[8] + a[3]*inv[12];
    float rd = 1.0f / det;
    float* o = minv + (size_t)idx * 16;
#pragma unroll
    for (int j = 0; j < 16; ++j) o[j] = inv[j] * rd;
}

// ========== fused flash attention: 8-wave blocks, 2-barrier pipelined staging ==========
// 56 KB LDS: single klds/vtlds (safe to overwrite after barrier A because each
// wave holds its full K/V fragment set in registers), double-buffered mlds
// (write pre-barrier), split per-q-tile P scratch (removes the P LDS
// round-trip WAR serialization). 2 barriers per chunk.
// BUG FIX vs rounds 6/8: ISSUE takes a CHUNK INDEX here (called with 0/1/kc+2);
// the body must scale by 64 keys (key = kb*64 + ...) and 256 f32x4 (Minv).
// Rounds 6/8 kept round-5's key-base-argument body -> loaded K/V rows
// [kc+1, kc+65) instead of [(kc+1)*64, ...): deterministic wrong output,
// identical absmax 2.5625 in both rounds. All arithmetic verbatim round-5.
__global__ __launch_bounds__(512) void k_attn_f(
    const float* __restrict__ qf, const float* __restrict__ kf_,
    const float* __restrict__ vf_, const float* __restrict__ minv,
    const float* __restrict__ lf, float* __restrict__ outp)
{
    __shared__ u16 klds[64 * 64];         // [key][c]   8 KB, XOR-swizzled 16B chunks
    __shared__ u16 vtlds[64 * 64];        // [c][key]   8 KB, swizzled
    __shared__ u16 pscr[8][2][16 * 64];   // per-wave, per-q-tile P  32 KB
    __shared__ float mlds[2][64 * 16];    // [buf] frame inverses     8 KB

    const int bh = blockIdx.x & 255;      // blocks bh and bh+256 share K/V (same XCD mod 8)
    const int g  = blockIdx.x >> 8;       // 0/1: which 256-row q half
    const int b  = bh >> 3;
    const int tid = threadIdx.x;
    const int wave = tid >> 6;
    const int lane = tid & 63;
    const int l16 = lane & 15;
    const int g4  = lane >> 4;
    const int keyg = tid >> 4;            // 0..31: key-group within chunk
    const int slot = tid & 15;            // channel quad

    const int q0w = g * 256 + wave * 32;  // wave covers 2 q-tiles

    const float QSC = 0.125f * 1.44269504f;     // 1/sqrt(C) * log2(e)

    // ---- Q prologue: transform own rows straight into MFMA B-fragments ----
    short8 bq[2][2];
#pragma unroll
    for (int t2 = 0; t2 < 2; ++t2) {
        int row = q0w + t2 * 16 + l16;
        const f32x4* Mp = (const f32x4*)(minv + ((size_t)b * S_ + row) * 16);
        f32x4 M0 = Mp[0], M1 = Mp[1], M2 = Mp[2], M3 = Mp[3];
        const f32x4* qrow = (const f32x4*)(qf + ((size_t)bh * S_ + row) * C_);
        uint32_t pk[8];
#pragma unroll
        for (int u = 0; u < 4; ++u) {
            int qd = (u < 2) ? (2 * g4 + u) : (8 + 2 * g4 + (u - 2));
            f32x4 x = qrow[qd];
            float y0, y1, y2, y3;
            if (qd < 4) { y0 = x[0]; y1 = x[1]; y2 = x[2]; y3 = x[3]; }
            else {
                y0 = M0[0]*x[0] + M0[1]*x[1] + M0[2]*x[2] + M0[3]*x[3];
                y1 = M1[0]*x[0] + M1[1]*x[1] + M1[2]*x[2] + M1[3]*x[3];
                y2 = M2[0]*x[0] + M2[1]*x[1] + M2[2]*x[2] + M2[3]*x[3];
                y3 = M3[0]*x[0] + M3[1]*x[1] + M3[2]*x[2] + M3[3]*x[3];
            }
            pk[2*u]   = pack_bf16(y0 * QSC, y1 * QSC);
            pk[2*u+1] = pack_bf16(y2 * QSC, y3 * QSC);
        }
        U8 a0; a0.u[0] = pk[0]; a0.u[1] = pk[1]; a0.u[2] = pk[2]; a0.u[3] = pk[3];
        U8 a1; a1.u[0] = pk[4]; a1.u[1] = pk[5]; a1.u[2] = pk[6]; a1.u[3] = pk[7];
        bq[t2][0] = a0.s; bq[t2][1] = a1.s;
    }

    float lrow[2] = {0.f, 0.f};
    f32x4 Ov[2][4];
#pragma unroll
    for (int t = 0; t < 2; ++t)
#pragma unroll
        for (int nb = 0; nb < 4; ++nb) Ov[t][nb] = (f32x4){0.f, 0.f, 0.f, 0.f};

    const float* kb_ = kf_ + (size_t)bh * S_ * C_;
    const float* vb_ = vf_ + (size_t)bh * S_ * C_;
    const float* mvb = minv + (size_t)b * S_ * 16;

    // chunk prefetch registers: f32 k/v (2x16B each) + slice of Minv (16B, tid<256)
    // kb is a CHUNK INDEX (0..7): keys [kb*64, kb*64+64), Minv floats [kb*1024, +1024)
    f32x4 krF[2], vrF[2], mF;
#define ISSUE(kb) do {                                                          \
    _Pragma("unroll")                                                           \
    for (int i = 0; i < 2; ++i) {                                               \
        int key = (kb) * 64 + keyg + 32 * i;                                    \
        krF[i] = *((const f32x4*)(kb_ + (size_t)key * C_) + slot);              \
        vrF[i] = *((const f32x4*)(vb_ + (size_t)key * C_) + slot);              \
    }                                                                           \
    if (tid < 256) mF = *((const f32x4*)(mvb) + (size_t)(kb) * 256 + tid);      \
} while (0)

// transform chunk held in krF/vrF (M from mlds[mb]) into klds/vtlds (single buf)
#define TRANSFORM(mb) do {                                                      \
    _Pragma("unroll")                                                           \
    for (int i = 0; i < 2; ++i) {                                               \
        int kl = keyg + 32 * i;                                                 \
        const f32x4* Mr = (const f32x4*)&mlds[mb][kl * 16];                     \
        f32x4 M0 = Mr[0], M1 = Mr[1], M2 = Mr[2], M3 = Mr[3];                   \
        {   /* K: eta * inv * eta */                                            \
            f32x4 x = krF[i];                                                   \
            float y0, y1, y2, y3;                                               \
            if (slot < 4) { y0 = x[0]; y1 = x[1]; y2 = x[2]; y3 = x[3]; }       \
            else {                                                              \
                float x0 = x[0], x1 = -x[1], x2 = -x[2], x3 = -x[3];            \
                y0 =   M0[0]*x0 + M0[1]*x1 + M0[2]*x2 + M0[3]*x3;               \
                y1 = -(M1[0]*x0 + M1[1]*x1 + M1[2]*x2 + M1[3]*x3);              \
                y2 = -(M2[0]*x0 + M2[1]*x1 + M2[2]*x2 + M2[3]*x3);              \
                y3 = -(M3[0]*x0 + M3[1]*x1 + M3[2]*x2 + M3[3]*x3);              \
            }                                                                   \
            u32x2 o; o.x = pack_bf16(y0, y1); o.y = pack_bf16(y2, y3);          \
            *(u32x2*)&klds[kl * 64 + (((slot >> 1) ^ (kl & 7)) << 3) + ((slot & 1) << 2)] = o; \
        }                                                                       \
        {   /* V: inv, then in-wave 4-key transpose into [c][key] */            \
            f32x4 x = vrF[i];                                                   \
            float y0, y1, y2, y3;                                               \
            if (slot < 4) { y0 = x[0]; y1 = x[1]; y2 = x[2]; y3 = x[3]; }       \
            else {                                                              \
                y0 = M0[0]*x[0] + M0[1]*x[1] + M0[2]*x[2] + M0[3]*x[3];         \
                y1 = M1[0]*x[0] + M1[1]*x[1] + M1[2]*x[2] + M1[3]*x[3];         \
                y2 = M2[0]*x[0] + M2[1]*x[1] + M2[2]*x[2] + M2[3]*x[3];         \
                y3 = M3[0]*x[0] + M3[1]*x[1] + M3[2]*x[2] + M3[3]*x[3];         \
            }                                                                   \
            uint32_t pk01 = pack_bf16(y0, y1);                                  \
            uint32_t pk23 = pack_bf16(y2, y3);                                  \
            int srow = lane >> 2;                                               \
            uint32_t r[4];                                                      \
            _Pragma("unroll")                                                   \
            for (int kk = 0; kk < 4; ++kk) {                                    \
                int src = kk * 16 + srow;                                       \
                uint32_t a01 = __shfl(pk01, src);                               \
                uint32_t a23 = __shfl(pk23, src);                               \
                uint32_t sel = (lane & 2) ? a23 : a01;                          \
                r[kk] = (lane & 1) ? (sel >> 16) : (sel & 0xffffu);             \
            }                                                                   \
            int c   = lane;                                                     \
            int kb4 = wave * 4 + 32 * i;                                        \
            u32x2 d; d.x = r[0] | (r[1] << 16); d.y = r[2] | (r[3] << 16);      \
            *(u32x2*)&vtlds[c * 64 + ((((kb4 >> 3)) ^ (c & 7)) << 3) + (kb4 & 7)] = d; \
        }                                                                       \
    }                                                                           \
} while (0)

    // ---- prologue: stage chunk 0, issue chunk 1 ----
    ISSUE(0);
    if (tid < 256) *((f32x4*)&mlds[0][tid * 4]) = mF;
    __syncthreads();
    TRANSFORM(0);
    ISSUE(1);
    __syncthreads();

    for (int kc = 0; kc < 8; ++kc) {
        // ---- hoisted fragments: whole K/V tile -> registers (shared by both q-tiles) ----
        short8 ka[4][2], va[4][2];
#pragma unroll
        for (int nb = 0; nb < 4; ++nb) {
            int R = nb * 16 + l16;
            const u16* kr = &klds[R * 64];
            ka[nb][0] = *(const short8*)(kr + ((g4 ^ (R & 7)) << 3));
            ka[nb][1] = *(const short8*)(kr + (((g4 + 4) ^ (R & 7)) << 3));
            const u16* vr = &vtlds[R * 64];
            va[nb][0] = *(const short8*)(vr + ((g4 ^ (R & 7)) << 3));
            va[nb][1] = *(const short8*)(vr + (((g4 + 4) ^ (R & 7)) << 3));
        }

        // ---- QK^T + exp2 + pack + P-write, per q-tile into its own half ----
#pragma unroll
        for (int t = 0; t < 2; ++t) {
            u16* pw = pscr[wave][t];
            f32x4 sT[4];
#pragma unroll
            for (int nb = 0; nb < 4; ++nb) {
                f32x4 acc = (f32x4){0.f, 0.f, 0.f, 0.f};
                acc = __builtin_amdgcn_mfma_f32_16x16x32_bf16(ka[nb][0], bq[t][0], acc, 0, 0, 0);
                acc = __builtin_amdgcn_mfma_f32_16x16x32_bf16(ka[nb][1], bq[t][1], acc, 0, 0, 0);
                sT[nb] = acc;
            }
            float rowsum = 0.f;
#pragma unroll
            for (int nb = 0; nb < 4; ++nb) {
                float e0 = __builtin_amdgcn_exp2f(sT[nb][0]);
                float e1 = __builtin_amdgcn_exp2f(sT[nb][1]);
                float e2 = __builtin_amdgcn_exp2f(sT[nb][2]);
                float e3 = __builtin_amdgcn_exp2f(sT[nb][3]);
                uint32_t pk01 = pack_bf16(e0, e1);
                uint32_t pk23 = pack_bf16(e2, e3);
                rowsum += (bflo(pk01) + bfhi(pk01)) + (bflo(pk23) + bfhi(pk23));
                u32x2 d; d.x = pk01; d.y = pk23;
                int phys = ((nb * 2 + (g4 >> 1)) ^ (l16 & 7));
                *(u32x2*)&pw[l16 * 64 + (phys << 3) + ((g4 & 1) << 2)] = d;
            }
            lrow[t] += rowsum;
        }

        // ---- PV: O^T += V^T P^T (t0's P-write latency drained under t1's pack) ----
#pragma unroll
        for (int t = 0; t < 2; ++t) {
            u16* pw = pscr[wave][t];
            short8 bp0 = *(const short8*)&pw[l16 * 64 + ((g4 ^ (l16 & 7)) << 3)];
            short8 bp1 = *(const short8*)&pw[l16 * 64 + (((g4 + 4) ^ (l16 & 7)) << 3)];
#pragma unroll
            for (int nb = 0; nb < 4; ++nb) {
                Ov[t][nb] = __builtin_amdgcn_mfma_f32_16x16x32_bf16(va[nb][0], bp0, Ov[t][nb], 0, 0, 0);
                Ov[t][nb] = __builtin_amdgcn_mfma_f32_16x16x32_bf16(va[nb][1], bp1, Ov[t][nb], 0, 0, 0);
            }
        }

        // ---- stage chunk kc+1 (overwrite single K/V buffers; frags are in regs) ----
        if (kc < 7) {
            const int mb = (kc + 1) & 1;
            if (tid < 256) *((f32x4*)&mlds[mb][tid * 4]) = mF;   // dbuf: safe pre-barrier
            __syncthreads();                      // A: all frag reads done; mlds[mb] visible
            TRANSFORM(mb);
            if (kc < 6) ISSUE(kc + 2);            // drains over next chunk's compute
            __syncthreads();                      // B: klds/vtlds ready
        }
    }

    // epilogue: reduce denominator (2 shfl), normalize, apply lframes, store f32
#pragma unroll
    for (int t = 0; t < 2; ++t) {
        float l = lrow[t];
        l += __shfl_xor(l, 16);
        l += __shfl_xor(l, 32);
        float il = 1.0f / l;
        int qglob = q0w + t * 16 + l16;
        const float* L = lf + ((size_t)(b * S_ + qglob)) * 16;
        float* ob = outp + ((size_t)(bh * S_ + qglob)) * C_;
#pragma unroll
        for (int nb = 0; nb < 4; ++nb) {
            float x0 = Ov[t][nb][0] * il, x1 = Ov[t][nb][1] * il,
                  x2 = Ov[t][nb][2] * il, x3 = Ov[t][nb][3] * il;
            float y0, y1, y2, y3;
            if (nb == 0) {       // scalar channels pass through
                y0 = x0; y1 = x1; y2 = x2; y3 = x3;
            } else {             // channel quad nb*16+g4*4 is one Lorentz 4-vector
                y0 = L[0]*x0 + L[1]*x1 + L[2]*x2  + L[3]*x3;
                y1 = L[4]*x0 + L[5]*x1 + L[6]*x2  + L[7]*x3;
                y2 = L[8]*x0 + L[9]*x1 + L[10]*x2 + L[11]*x3;
                y3 = L[12]*x0 + L[13]*x1 + L[14]*x2 + L[15]*x3;
            }
            *(f32x4*)(ob + nb * 16 + g4 * 4) = (f32x4){y0, y1, y2, y3};
        }
    }
}

extern "C" void kernel_launch(void* const* d_in, const int* in_sizes, int n_in,
                              void* d_out, int out_size, void* d_ws, size_t ws_size,
                              hipStream_t stream) {
    const float* q  = (const float*)d_in[0];
    const float* k  = (const float*)d_in[1];
    const float* v  = (const float*)d_in[2];
    const float* lf = (const float*)d_in[3];
    float* out = (float*)d_out;

    float* minv = (float*)d_ws;            // 1 MiB: 16K inverted frames

    k_inv<<<B_ * S_ / 64, 64, 0, stream>>>(lf, minv);
    k_attn_f<<<512, 512, 0, stream>>>(q, k, v, minv, lf, out);
}

// Round 10
// 164.972 us; speedup vs baseline: 1.0041x; 1.0041x over previous
//
#include <hip/hip_runtime.h>
#include <hip/hip_bf16.h>
#include <cstdint>

typedef unsigned short u16;
typedef __attribute__((ext_vector_type(8))) short short8;
typedef __attribute__((ext_vector_type(4))) float f32x4;

#define B_ 32
#define H_ 8
#define S_ 512
#define C_ 64

struct alignas(8) u32x2 { uint32_t x, y; };
union U8 { short8 s; uint32_t u[4]; };

__device__ __forceinline__ u16 f2bf(float f) {
    uint32_t u = __builtin_bit_cast(uint32_t, f);
    u += 0x7fffu + ((u >> 16) & 1u);   // RNE
    return (u16)(u >> 16);
}

#if __has_builtin(__builtin_amdgcn_cvt_pk_bf16_f32)
__device__ __forceinline__ uint32_t pack_bf16(float a, float b) {
    auto r = __builtin_amdgcn_cvt_pk_bf16_f32(a, b);   // v_cvt_pk_bf16_f32 (RNE)
    return __builtin_bit_cast(uint32_t, r);
}
#else
__device__ __forceinline__ uint32_t pack_bf16(float a, float b) {
    return (uint32_t)f2bf(a) | ((uint32_t)f2bf(b) << 16);
}
#endif

__device__ __forceinline__ float bfhi(uint32_t pk) {   // high bf16 -> f32
    return __builtin_bit_cast(float, pk & 0xffff0000u);
}
__device__ __forceinline__ float bflo(uint32_t pk) {   // low bf16 -> f32
    return __builtin_bit_cast(float, pk << 16);
}

// ================= k_inv: one thread per (b,n) frame inverse =================
__global__ __launch_bounds__(64) void k_inv(
    const float* __restrict__ lf, float* __restrict__ minv)
{
    const int idx = blockIdx.x * 64 + threadIdx.x;   // 0 .. B*S-1
    const float* m = lf + (size_t)idx * 16;
    float a[16];
#pragma unroll
    for (int j = 0; j < 16; ++j) a[j] = m[j];
    float inv[16];
    inv[0]  =  a[5]*a[10]*a[15] - a[5]*a[11]*a[14] - a[9]*a[6]*a[15] + a[9]*a[7]*a[14] + a[13]*a[6]*a[11] - a[13]*a[7]*a[10];
    inv[4]  = -a[4]*a[10]*a[15] + a[4]*a[11]*a[14] + a[8]*a[6]*a[15] - a[8]*a[7]*a[14] - a[12]*a[6]*a[11] + a[12]*a[7]*a[10];
    inv[8]  =  a[4]*a[9]*a[15] - a[4]*a[11]*a[13] - a[8]*a[5]*a[15] + a[8]*a[7]*a[13] + a[12]*a[5]*a[11] - a[12]*a[7]*a[9];
    inv[12] = -a[4]*a[9]*a[14] + a[4]*a[10]*a[13] + a[8]*a[5]*a[14] - a[8]*a[6]*a[13] - a[12]*a[5]*a[10] + a[12]*a[6]*a[9];
    inv[1]  = -a[1]*a[10]*a[15] + a[1]*a[11]*a[14] + a[9]*a[2]*a[15] - a[9]*a[3]*a[14] - a[13]*a[2]*a[11] + a[13]*a[3]*a[10];
    inv[5]  =  a[0]*a[10]*a[15] - a[0]*a[11]*a[14] - a[8]*a[2]*a[15] + a[8]*a[3]*a[14] + a[12]*a[2]*a[11] - a[12]*a[3]*a[10];
    inv[9]  = -a[0]*a[9]*a[15] + a[0]*a[11]*a[13] + a[8]*a[1]*a[15] - a[8]*a[3]*a[13] - a[12]*a[1]*a[11] + a[12]*a[3]*a[9];
    inv[13] =  a[0]*a[9]*a[14] - a[0]*a[10]*a[13] - a[8]*a[1]*a[14] + a[8]*a[2]*a[13] + a[12]*a[1]*a[10] - a[12]*a[2]*a[9];
    inv[2]  =  a[1]*a[6]*a[15] - a[1]*a[7]*a[14] - a[5]*a[2]*a[15] + a[5]*a[3]*a[14] + a[13]*a[2]*a[7] - a[13]*a[3]*a[6];
    inv[6]  = -a[0]*a[6]*a[15] + a[0]*a[7]*a[14] + a[4]*a[2]*a[15] - a[4]*a[3]*a[14] - a[12]*a[2]*a[7] + a[12]*a[3]*a[6];
    inv[10] =  a[0]*a[5]*a[15] - a[0]*a[7]*a[13] - a[4]*a[1]*a[15] + a[4]*a[3]*a[13] + a[12]*a[1]*a[7] - a[12]*a[3]*a[5];
    inv[14] = -a[0]*a[5]*a[14] + a[0]*a[6]*a[13] + a[4]*a[1]*a[14] - a[4]*a[2]*a[13] - a[12]*a[1]*a[6] + a[12]*a[2]*a[5];
    inv[3]  = -a[1]*a[6]*a[11] + a[1]*a[7]*a[10] + a[5]*a[2]*a[11] - a[5]*a[3]*a[10] - a[9]*a[2]*a[7] + a[9]*a[3]*a[6];
    inv[7]  =  a[0]*a[6]*a[11] - a[0]*a[7]*a[10] - a[4]*a[2]*a[11] + a[4]*a[3]*a[10] + a[8]*a[2]*a[7] - a[8]*a[3]*a[6];
    inv[11] = -a[0]*a[5]*a[11] + a[0]*a[7]*a[9] + a[4]*a[1]*a[11] - a[4]*a[3]*a[9] - a[8]*a[1]*a[7] + a[8]*a[3]*a[5];
    inv[15] =  a[0]*a[5]*a[10] - a[0]*a[6]*a[9] - a[4]*a[1]*a[10] + a[4]*a[2]*a[9] + a[8]*a[1]*a[6] - a[8]*a[2]*a[5];
    float det = a[0]*inv[0] + a[1]*inv[4] + a[2]*inv[8] + a[3]*inv[12];
    float rd = 1.0f / det;
    float* o = minv + (size_t)idx * 16;
#pragma unroll
    for (int j = 0; j < 16; ++j) o[j] = inv[j] * rd;
}

// ========== fused flash attention: transform/compute INTERLEAVED in one phase ==========
// vs round 9 (same 56 KB LDS, same arithmetic): TRANSFORM(kc+1) + ISSUE(kc+2)
// are moved INTO the compute phase (after barrier A, alongside QK/softmax/PV of
// chunk kc, single basic block -> scheduler interleaves transform VALU/shfl with
// MFMA/exp2 stall slots). Rounds 5 & 9 proved barrier count/P-WAR were not the
// bottleneck (67.4 vs 68.0 us); the exposed serial TRANSFORM phase and the
// vmcnt(0)-at-barrier load drain are the target here. Loop peeled (kc<6 /
// kc==6 / kc==7) so the hot body has no internal branches.
__global__ __launch_bounds__(512) void k_attn_f(
    const float* __restrict__ qf, const float* __restrict__ kf_,
    const float* __restrict__ vf_, const float* __restrict__ minv,
    const float* __restrict__ lf, float* __restrict__ outp)
{
    __shared__ u16 klds[64 * 64];         // [key][c]   8 KB, XOR-swizzled 16B chunks
    __shared__ u16 vtlds[64 * 64];        // [c][key]   8 KB, swizzled
    __shared__ u16 pscr[8][2][16 * 64];   // per-wave, per-q-tile P  32 KB
    __shared__ float mlds[2][64 * 16];    // [buf] frame inverses     8 KB

    const int bh = blockIdx.x & 255;      // blocks bh and bh+256 share K/V (same XCD mod 8)
    const int g  = blockIdx.x >> 8;       // 0/1: which 256-row q half
    const int b  = bh >> 3;
    const int tid = threadIdx.x;
    const int wave = tid >> 6;
    const int lane = tid & 63;
    const int l16 = lane & 15;
    const int g4  = lane >> 4;
    const int keyg = tid >> 4;            // 0..31: key-group within chunk
    const int slot = tid & 15;            // channel quad

    const int q0w = g * 256 + wave * 32;  // wave covers 2 q-tiles

    const float QSC = 0.125f * 1.44269504f;     // 1/sqrt(C) * log2(e)

    // ---- Q prologue: transform own rows straight into MFMA B-fragments ----
    short8 bq[2][2];
#pragma unroll
    for (int t2 = 0; t2 < 2; ++t2) {
        int row = q0w + t2 * 16 + l16;
        const f32x4* Mp = (const f32x4*)(minv + ((size_t)b * S_ + row) * 16);
        f32x4 M0 = Mp[0], M1 = Mp[1], M2 = Mp[2], M3 = Mp[3];
        const f32x4* qrow = (const f32x4*)(qf + ((size_t)bh * S_ + row) * C_);
        uint32_t pk[8];
#pragma unroll
        for (int u = 0; u < 4; ++u) {
            int qd = (u < 2) ? (2 * g4 + u) : (8 + 2 * g4 + (u - 2));
            f32x4 x = qrow[qd];
            float y0, y1, y2, y3;
            if (qd < 4) { y0 = x[0]; y1 = x[1]; y2 = x[2]; y3 = x[3]; }
            else {
                y0 = M0[0]*x[0] + M0[1]*x[1] + M0[2]*x[2] + M0[3]*x[3];
                y1 = M1[0]*x[0] + M1[1]*x[1] + M1[2]*x[2] + M1[3]*x[3];
                y2 = M2[0]*x[0] + M2[1]*x[1] + M2[2]*x[2] + M2[3]*x[3];
                y3 = M3[0]*x[0] + M3[1]*x[1] + M3[2]*x[2] + M3[3]*x[3];
            }
            pk[2*u]   = pack_bf16(y0 * QSC, y1 * QSC);
            pk[2*u+1] = pack_bf16(y2 * QSC, y3 * QSC);
        }
        U8 a0; a0.u[0] = pk[0]; a0.u[1] = pk[1]; a0.u[2] = pk[2]; a0.u[3] = pk[3];
        U8 a1; a1.u[0] = pk[4]; a1.u[1] = pk[5]; a1.u[2] = pk[6]; a1.u[3] = pk[7];
        bq[t2][0] = a0.s; bq[t2][1] = a1.s;
    }

    float lrow[2] = {0.f, 0.f};
    f32x4 Ov[2][4];
#pragma unroll
    for (int t = 0; t < 2; ++t)
#pragma unroll
        for (int nb = 0; nb < 4; ++nb) Ov[t][nb] = (f32x4){0.f, 0.f, 0.f, 0.f};

    const float* kb_ = kf_ + (size_t)bh * S_ * C_;
    const float* vb_ = vf_ + (size_t)bh * S_ * C_;
    const float* mvb = minv + (size_t)b * S_ * 16;

    // chunk prefetch registers: f32 k/v (2x16B each) + slice of Minv (16B, tid<256)
    // kb is a CHUNK INDEX (0..7): keys [kb*64, kb*64+64), Minv floats [kb*1024, +1024)
    f32x4 krF[2], vrF[2], mF;
#define ISSUE(kb) do {                                                          \
    _Pragma("unroll")                                                           \
    for (int i = 0; i < 2; ++i) {                                               \
        int key = (kb) * 64 + keyg + 32 * i;                                    \
        krF[i] = *((const f32x4*)(kb_ + (size_t)key * C_) + slot);              \
        vrF[i] = *((const f32x4*)(vb_ + (size_t)key * C_) + slot);              \
    }                                                                           \
    if (tid < 256) mF = *((const f32x4*)(mvb) + (size_t)(kb) * 256 + tid);      \
} while (0)

#define MLDSW(mb) do {                                                          \
    if (tid < 256) *((f32x4*)&mlds[mb][tid * 4]) = mF;                          \
} while (0)

// transform chunk held in krF/vrF (M from mlds[mb]) into klds/vtlds (single buf)
#define TRANSFORM(mb) do {                                                      \
    _Pragma("unroll")                                                           \
    for (int i = 0; i < 2; ++i) {                                               \
        int kl = keyg + 32 * i;                                                 \
        const f32x4* Mr = (const f32x4*)&mlds[mb][kl * 16];                     \
        f32x4 M0 = Mr[0], M1 = Mr[1], M2 = Mr[2], M3 = Mr[3];                   \
        {   /* K: eta * inv * eta */                                            \
            f32x4 x = krF[i];                                                   \
            float y0, y1, y2, y3;                                               \
            if (slot < 4) { y0 = x[0]; y1 = x[1]; y2 = x[2]; y3 = x[3]; }       \
            else {                                                              \
                float x0 = x[0], x1 = -x[1], x2 = -x[2], x3 = -x[3];            \
                y0 =   M0[0]*x0 + M0[1]*x1 + M0[2]*x2 + M0[3]*x3;               \
                y1 = -(M1[0]*x0 + M1[1]*x1 + M1[2]*x2 + M1[3]*x3);              \
                y2 = -(M2[0]*x0 + M2[1]*x1 + M2[2]*x2 + M2[3]*x3);              \
                y3 = -(M3[0]*x0 + M3[1]*x1 + M3[2]*x2 + M3[3]*x3);              \
            }                                                                   \
            u32x2 o; o.x = pack_bf16(y0, y1); o.y = pack_bf16(y2, y3);          \
            *(u32x2*)&klds[kl * 64 + (((slot >> 1) ^ (kl & 7)) << 3) + ((slot & 1) << 2)] = o; \
        }                                                                       \
        {   /* V: inv, then in-wave 4-key transpose into [c][key] */            \
            f32x4 x = vrF[i];                                                   \
            float y0, y1, y2, y3;                                               \
            if (slot < 4) { y0 = x[0]; y1 = x[1]; y2 = x[2]; y3 = x[3]; }       \
            else {                                                              \
                y0 = M0[0]*x[0] + M0[1]*x[1] + M0[2]*x[2] + M0[3]*x[3];         \
                y1 = M1[0]*x[0] + M1[1]*x[1] + M1[2]*x[2] + M1[3]*x[3];         \
                y2 = M2[0]*x[0] + M2[1]*x[1] + M2[2]*x[2] + M2[3]*x[3];         \
                y3 = M3[0]*x[0] + M3[1]*x[1] + M3[2]*x[2] + M3[3]*x[3];         \
            }                                                                   \
            uint32_t pk01 = pack_bf16(y0, y1);                                  \
            uint32_t pk23 = pack_bf16(y2, y3);                                  \
            int srow = lane >> 2;                                               \
            uint32_t r[4];                                                      \
            _Pragma("unroll")                                                   \
            for (int kk = 0; kk < 4; ++kk) {                                    \
                int src = kk * 16 + srow;                                       \
                uint32_t a01 = __shfl(pk01, src);                               \
                uint32_t a23 = __shfl(pk23, src);                               \
                uint32_t sel = (lane & 2) ? a23 : a01;                          \
                r[kk] = (lane & 1) ? (sel >> 16) : (sel & 0xffffu);             \
            }                                                                   \
            int c   = lane;                                                     \
            int kb4 = wave * 4 + 32 * i;                                        \
            u32x2 d; d.x = r[0] | (r[1] << 16); d.y = r[2] | (r[3] << 16);      \
            *(u32x2*)&vtlds[c * 64 + ((((kb4 >> 3)) ^ (c & 7)) << 3) + (kb4 & 7)] = d; \
        }                                                                       \
    }                                                                           \
} while (0)

// hoist whole K/V tile into registers (shared by both q-tiles)
#define FRAGS() do {                                                            \
    _Pragma("unroll")                                                           \
    for (int nb = 0; nb < 4; ++nb) {                                            \
        int R = nb * 16 + l16;                                                  \
        const u16* kr = &klds[R * 64];                                          \
        ka[nb][0] = *(const short8*)(kr + ((g4 ^ (R & 7)) << 3));               \
        ka[nb][1] = *(const short8*)(kr + (((g4 + 4) ^ (R & 7)) << 3));         \
        const u16* vr = &vtlds[R * 64];                                         \
        va[nb][0] = *(const short8*)(vr + ((g4 ^ (R & 7)) << 3));               \
        va[nb][1] = *(const short8*)(vr + (((g4 + 4) ^ (R & 7)) << 3));         \
    }                                                                           \
} while (0)

// QK^T + exp2 + pack + P-write + rowsum, then PV, both q-tiles (regs only + wave-private pscr)
#define COMPUTE() do {                                                          \
    _Pragma("unroll")                                                           \
    for (int t = 0; t < 2; ++t) {                                               \
        u16* pw = pscr[wave][t];                                                \
        f32x4 sT[4];                                                            \
        _Pragma("unroll")                                                       \
        for (int nb = 0; nb < 4; ++nb) {                                        \
            f32x4 acc = (f32x4){0.f, 0.f, 0.f, 0.f};                            \
            acc = __builtin_amdgcn_mfma_f32_16x16x32_bf16(ka[nb][0], bq[t][0], acc, 0, 0, 0); \
            acc = __builtin_amdgcn_mfma_f32_16x16x32_bf16(ka[nb][1], bq[t][1], acc, 0, 0, 0); \
            sT[nb] = acc;                                                       \
        }                                                                       \
        float rowsum = 0.f;                                                     \
        _Pragma("unroll")                                                       \
        for (int nb = 0; nb < 4; ++nb) {                                        \
            float e0 = __builtin_amdgcn_exp2f(sT[nb][0]);                       \
            float e1 = __builtin_amdgcn_exp2f(sT[nb][1]);                       \
            float e2 = __builtin_amdgcn_exp2f(sT[nb][2]);                       \
            float e3 = __builtin_amdgcn_exp2f(sT[nb][3]);                       \
            uint32_t pk01 = pack_bf16(e0, e1);                                  \
            uint32_t pk23 = pack_bf16(e2, e3);                                  \
            rowsum += (bflo(pk01) + bfhi(pk01)) + (bflo(pk23) + bfhi(pk23));    \
            u32x2 d; d.x = pk01; d.y = pk23;                                    \
            int phys = ((nb * 2 + (g4 >> 1)) ^ (l16 & 7));                      \
            *(u32x2*)&pw[l16 * 64 + (phys << 3) + ((g4 & 1) << 2)] = d;         \
        }                                                                       \
        lrow[t] += rowsum;                                                      \
    }                                                                           \
    _Pragma("unroll")                                                           \
    for (int t = 0; t < 2; ++t) {                                               \
        u16* pw = pscr[wave][t];                                                \
        short8 bp0 = *(const short8*)&pw[l16 * 64 + ((g4 ^ (l16 & 7)) << 3)];   \
        short8 bp1 = *(const short8*)&pw[l16 * 64 + (((g4 + 4) ^ (l16 & 7)) << 3)]; \
        _Pragma("unroll")                                                       \
        for (int nb = 0; nb < 4; ++nb) {                                        \
            Ov[t][nb] = __builtin_amdgcn_mfma_f32_16x16x32_bf16(va[nb][0], bp0, Ov[t][nb], 0, 0, 0); \
            Ov[t][nb] = __builtin_amdgcn_mfma_f32_16x16x32_bf16(va[nb][1], bp1, Ov[t][nb], 0, 0, 0); \
        }                                                                       \
    }                                                                           \
} while (0)

    short8 ka[4][2], va[4][2];

    // ---- prologue: stage chunk 0, issue chunk 1 ----
    ISSUE(0);
    MLDSW(0);
    __syncthreads();
    TRANSFORM(0);
    ISSUE(1);
    __syncthreads();

    // ---- main loop kc = 0..5: branch-free body, transform/issue/compute in ONE phase ----
    for (int kc = 0; kc < 6; ++kc) {
        const int mb = (kc + 1) & 1;
        FRAGS();                              // chunk kc -> regs (reads klds/vtlds)
        MLDSW(mb);                            // mF = chunk kc+1 Minv (dbuf, pre-barrier)
        __syncthreads();                      // A: frag reads done; mlds[mb] visible
        TRANSFORM(mb);                        // stage chunk kc+1 (overwrites klds/vtlds)
        ISSUE(kc + 2);                        // loads drain over COMPUTE below
        COMPUTE();                            // chunk kc QK/softmax/PV (regs + pscr only)
        __syncthreads();                      // B: klds/vtlds ready for next FRAGS
    }
    // ---- kc == 6: no further ISSUE ----
    {
        FRAGS();
        MLDSW(1);                             // chunk 7 Minv -> mlds[1]
        __syncthreads();
        TRANSFORM(1);                         // stage chunk 7
        COMPUTE();                            // chunk 6
        __syncthreads();
    }
    // ---- kc == 7: compute only ----
    {
        FRAGS();
        COMPUTE();
    }

    // epilogue: reduce denominator (2 shfl), normalize, apply lframes, store f32
#pragma unroll
    for (int t = 0; t < 2; ++t) {
        float l = lrow[t];
        l += __shfl_xor(l, 16);
        l += __shfl_xor(l, 32);
        float il = 1.0f / l;
        int qglob = q0w + t * 16 + l16;
        const float* L = lf + ((size_t)(b * S_ + qglob)) * 16;
        float* ob = outp + ((size_t)(bh * S_ + qglob)) * C_;
#pragma unroll
        for (int nb = 0; nb < 4; ++nb) {
            float x0 = Ov[t][nb][0] * il, x1 = Ov[t][nb][1] * il,
                  x2 = Ov[t][nb][2] * il, x3 = Ov[t][nb][3] * il;
            float y0, y1, y2, y3;
            if (nb == 0) {       // scalar channels pass through
                y0 = x0; y1 = x1; y2 = x2; y3 = x3;
            } else {             // channel quad nb*16+g4*4 is one Lorentz 4-vector
                y0 = L[0]*x0 + L[1]*x1 + L[2]*x2  + L[3]*x3;
                y1 = L[4]*x0 + L[5]*x1 + L[6]*x2  + L[7]*x3;
                y2 = L[8]*x0 + L[9]*x1 + L[10]*x2 + L[11]*x3;
                y3 = L[12]*x0 + L[13]*x1 + L[14]*x2 + L[15]*x3;
            }
            *(f32x4*)(ob + nb * 16 + g4 * 4) = (f32x4){y0, y1, y2, y3};
        }
    }
}

extern "C" void kernel_launch(void* const* d_in, const int* in_sizes, int n_in,
                              void* d_out, int out_size, void* d_ws, size_t ws_size,
                              hipStream_t stream) {
    const float* q  = (const float*)d_in[0];
    const float* k  = (const float*)d_in[1];
    const float* v  = (const float*)d_in[2];
    const float* lf = (const float*)d_in[3];
    float* out = (float*)d_out;

    float* minv = (float*)d_ws;            // 1 MiB: 16K inverted frames

    k_inv<<<B_ * S_ / 64, 64, 0, stream>>>(lf, minv);
    k_attn_f<<<512, 512, 0, stream>>>(q, k, v, minv, lf, out);
}